// Round 21
// baseline (1005.185 us; speedup 1.0000x reference)
//
#include <hip/hip_runtime.h>
#include <hip/hip_bf16.h>

// MoE experts MLP: E=8, T=2048, H=2048, F=4096, fp32 in/out.
// r21: gateup is restructured as a SINGLE 256x256 GEMM identical to the down
// kernel (which measures 1374 TF vs dual-gateup's 1034): W1T/W2T are
// interleaved at 16-column granularity into W12 [2F][H] during the transpose
// pre-pass (weight col f of W1 -> row (f>>4)*32+(f&15); W2 -> +16). Within a
// wave, j-frag parity = gate/up for the SAME f and rows in the SAME thread,
// so the silu fuse is thread-local. Down kernel byte-identical to r18.
// GEMM structure (both): BK=32, 512 thr/8 waves (2Mx4N, 128x64/wave),
// 3-buffer LDS rotation, distance-2 prefetch, counted vmcnt(4) (0 at tail),
// 2-phase K-step, global_load_lds(16B) pre-swizzled source (conflict-free
// XOR swizzle), setprio, XCD COLUMN grouping, launch_bounds(512,2), B=4.

#define EXPERTS 8
#define TOK 2048
#define HID 2048
#define FFN 4096

#define BKQ 32

typedef float f32x4 __attribute__((ext_vector_type(4)));
typedef __bf16 bf16x8 __attribute__((ext_vector_type(8)));

#if defined(__has_builtin)
#if __has_builtin(__builtin_amdgcn_global_load_lds)
#define HAVE_GLL 1
#endif
#endif

__device__ __forceinline__ void gload_lds16(const __bf16* g, __bf16* l, int lane) {
#ifdef HAVE_GLL
    __builtin_amdgcn_global_load_lds((const __attribute__((address_space(1))) void*)g,
                                     (__attribute__((address_space(3))) void*)l,
                                     16, 0, 0);
#else
    bf16x8 v = *(const bf16x8*)g;
    *(bf16x8*)(l + lane * 8) = v;
#endif
}

// BK=32 rows are 4 octets; swizzle o ^ ((row>>1)&3): conflict-free (measured 0).
__device__ __forceinline__ bf16x8 ldfrag32(const __bf16* s, int row, int fq) {
    return *(const bf16x8*)(s + row * BKQ + ((fq ^ ((row >> 1) & 3)) << 3));
}

// Stage 256x32 bf16 tile (2 gload_lds / thread, 512 threads).
__device__ __forceinline__ void stage256(__bf16* dst, const __bf16* src, size_t ld, int tid) {
    const int w = tid >> 6, l = tid & 63;
    const int ri = l >> 2, o = l & 3;
#pragma unroll
    for (int q = 0; q < 2; ++q) {
        const int row = q * 128 + w * 16 + ri;
        gload_lds16(src + (size_t)row * ld + ((o ^ ((row >> 1) & 3)) << 3),
                    dst + (size_t)(q * 128 + w * 16) * BKQ, l);
    }
}

// -------- merged transpose+cvt --------
// m=0: W1 [H][F] -> W12 interleaved rows (f>>4)*32+(f&15)      [2F][H]
// m=1: W2 [H][F] -> W12 interleaved rows (f>>4)*32+16+(f&15)   [2F][H]
// m=2: W3 [F][H] -> W3T [H][F] (plain transpose)
__global__ __launch_bounds__(256) void transpose_all_kernel(
    const float* __restrict__ W1, const float* __restrict__ W2,
    const float* __restrict__ W3, __bf16* __restrict__ wsb,
    int e_base, size_t slotElems)
{
    __shared__ float lds[64 * 68];
    const size_t MAT = (size_t)HID * FFN;
    const int t = threadIdx.x;
    const int m = blockIdx.y;
    const int e = e_base + blockIdx.z;

    const float* src;
    __bf16* dst;
    int C, csh;   // src is [R][C]
    if (m == 0)      { src = W1 + (size_t)e * MAT; dst = wsb + (size_t)blockIdx.z * slotElems;           C = FFN; csh = 6; }
    else if (m == 1) { src = W2 + (size_t)e * MAT; dst = wsb + (size_t)blockIdx.z * slotElems;           C = FFN; csh = 6; }
    else             { src = W3 + (size_t)e * MAT; dst = wsb + (size_t)blockIdx.z * slotElems + 2 * MAT; C = HID; csh = 5; }
    const int R = (m == 2) ? FFN : HID;
    const int bx = blockIdx.x & ((1 << csh) - 1);
    const int by = blockIdx.x >> csh;
    const int c0 = bx * 64, r0 = by * 64;

    const int rr = t >> 4;
    const int cc = (t & 15) * 4;
#pragma unroll
    for (int p = 0; p < 4; ++p) {
        const int row = p * 16 + rr;
        f32x4 v = *(const f32x4*)(src + (size_t)(r0 + row) * C + c0 + cc);
        *(f32x4*)&lds[row * 68 + (cc ^ (((row >> 3) & 7) << 2))] = v;
    }
    __syncthreads();
    const int o  = t & 7;
    const int c2 = t >> 3;
#pragma unroll
    for (int q = 0; q < 2; ++q) {
        const int c = q * 32 + c2;
        bf16x8 b;
#pragma unroll
        for (int j = 0; j < 8; ++j) {
            b[j] = (__bf16)lds[(8 * o + j) * 68 + (c ^ (o << 2))];
        }
        const int gcol = c0 + c;
        size_t drow;
        if (m == 2) drow = (size_t)gcol;                               // W3T row
        else        drow = (size_t)((gcol >> 4) * 32 + m * 16 + (gcol & 15)); // W12 interleaved
        *(bf16x8*)(dst + drow * R + r0 + 8 * o) = b;
    }
}

// -------- elementwise fp32 -> bf16 --------
__global__ __launch_bounds__(256) void cvt_kernel(const float* __restrict__ src,
                                                  __bf16* __restrict__ dst, size_t n) {
    const size_t i = ((size_t)blockIdx.x * 256 + threadIdx.x) * 8;
    if (i >= n) return;
    f32x4 v0 = *(const f32x4*)(src + i);
    f32x4 v1 = *(const f32x4*)(src + i + 4);
    bf16x8 b;
#pragma unroll
    for (int k = 0; k < 4; ++k) { b[k] = (__bf16)v0[k]; b[4 + k] = (__bf16)v1[k]; }
    *(bf16x8*)(dst + i) = b;
}

// ---------------- gateup: single GEMM [T]x[2F], 256x256, BK=32 --------------
// Structure identical to down_kernel; epilogue fuses silu via j-parity.
#define BMG 256
#define BNG 256
#define GXG (2 * FFN / BNG)          // 32
#define ASZ_G (BMG * BKQ)            // 8192 elems
#define BUF_G (2 * ASZ_G)            // 16384 elems = 32 KiB

__global__ __launch_bounds__(512, 2) void gateup_kernel(
    const __bf16* __restrict__ Xb, const __bf16* __restrict__ wsb,
    const float* __restrict__ b1, const float* __restrict__ b2,
    int e_base, size_t slotElems)
{
    __shared__ __align__(16) __bf16 lds[3 * BUF_G];   // 96 KiB
    const size_t MAT = (size_t)HID * FFN;
    const int tid = threadIdx.x;

    // bijective XCD swizzle (nwg=256); column decomposition: W12 panels pinned.
    int f = blockIdx.y * GXG + blockIdx.x;
    f = (f & 7) * ((GXG * (TOK / BMG)) >> 3) + (f >> 3);
    const int bx = f >> 3;                 // 0..31
    const int by = f & 7;                  // 0..7

    const int e  = e_base + blockIdx.z;
    const int m0 = by * BMG;
    const int n0 = bx * BNG;               // interleaved col base

    const __bf16* base = wsb + (size_t)blockIdx.z * slotElems;
    const __bf16* gA   = Xb + (size_t)(e * TOK + m0) * HID;
    const __bf16* gB   = base + (size_t)n0 * HID;             // W12 [2F][H]

    const int w = tid >> 6, lane = tid & 63;
    const int wm = w >> 2, wn = w & 3;          // 2M x 4N waves, per-wave 128x64
    const int fr = lane & 15, fq = lane >> 4;

    f32x4 acc[8][4] = {};

    const int NT = HID / BKQ;  // 64

#pragma unroll
    for (int t0 = 0; t0 < 2; ++t0) {
        __bf16* d = lds + t0 * BUF_G;
        const size_t ko = (size_t)t0 * BKQ;
        stage256(d, gA + ko, HID, tid);
        stage256(d + ASZ_G, gB + ko, HID, tid);
    }
    asm volatile("s_waitcnt vmcnt(4)" ::: "memory");
    __builtin_amdgcn_s_barrier();

    int cur = 0;
    for (int t = 0; t < NT; ++t) {
        const int nb = (cur == 0) ? 2 : cur - 1;   // (cur+2)%3
        __bf16* d = lds + nb * BUF_G;
        const size_t ko2 = (size_t)(t + 2) * BKQ;
        const __bf16* bufA = lds + cur * BUF_G;
        const __bf16* bufB = bufA + ASZ_G;

        // ---- phase A: m-half 0 ----
        bf16x8 a0[4], b[4];
#pragma unroll
        for (int i = 0; i < 4; ++i) a0[i] = ldfrag32(bufA, wm * 128 + i * 16 + fr, fq);
#pragma unroll
        for (int j = 0; j < 4; ++j) b[j] = ldfrag32(bufB, wn * 64 + j * 16 + fr, fq);
        if (t + 2 < NT) stage256(d, gA + ko2, HID, tid);           // 2 loads
        asm volatile("" ::: "memory");
        __builtin_amdgcn_s_barrier();
        __builtin_amdgcn_s_setprio(1);
#pragma unroll
        for (int j = 0; j < 4; ++j)
#pragma unroll
            for (int i = 0; i < 4; ++i)
                acc[i][j] = __builtin_amdgcn_mfma_f32_16x16x32_bf16(a0[i], b[j], acc[i][j], 0, 0, 0);
        __builtin_amdgcn_s_setprio(0);

        // ---- phase B: m-half 1 ----
        bf16x8 a1[4];
#pragma unroll
        for (int i = 0; i < 4; ++i) a1[i] = ldfrag32(bufA, wm * 128 + (i + 4) * 16 + fr, fq);
        if (t + 2 < NT) stage256(d + ASZ_G, gB + ko2, HID, tid);   // 2 loads
        if (t + 1 < NT) {
            if (t + 2 < NT) asm volatile("s_waitcnt vmcnt(4)" ::: "memory");
            else            asm volatile("s_waitcnt vmcnt(0)" ::: "memory");
        }
        asm volatile("" ::: "memory");
        __builtin_amdgcn_s_barrier();
        __builtin_amdgcn_s_setprio(1);
#pragma unroll
        for (int j = 0; j < 4; ++j)
#pragma unroll
            for (int i = 0; i < 4; ++i)
                acc[i + 4][j] = __builtin_amdgcn_mfma_f32_16x16x32_bf16(a1[i], b[j], acc[i + 4][j], 0, 0, 0);
        __builtin_amdgcn_s_setprio(0);

        cur = (cur == 2) ? 0 : cur + 1;
    }

    // epilogue: j even = gate, j odd = up (same f, same rows, same thread).
    // f = n0/2 + wn*32 + (j>>1)*16 + fr
    __bf16* gH = (__bf16*)(base + 3 * MAT) + (size_t)m0 * FFN;
    const int fb = (n0 >> 1) + wn * 32;
#pragma unroll
    for (int p = 0; p < 2; ++p) {
        const int fcol = fb + p * 16 + fr;
        const float bb1 = b1[(size_t)e * FFN + fcol];
        const float bb2 = b2[(size_t)e * FFN + fcol];
#pragma unroll
        for (int i = 0; i < 8; ++i) {
#pragma unroll
            for (int r = 0; r < 4; ++r) {
                const int row = wm * 128 + i * 16 + fq * 4 + r;
                const float g = acc[i][2 * p][r] + bb1;
                const float u = acc[i][2 * p + 1][r] + bb2;
                const float s = g / (1.0f + __expf(-g));
                gH[(size_t)row * FFN + fcol] = (__bf16)(s * u);
            }
        }
    }
}

// ---------------- down: GEMM 256x256, BK=32, 3-buf pipeline (r18) -----------
#define BMD 256
#define BND 256
#define GXD (HID / BND)              // 8
#define ASZ_D (BMD * BKQ)            // 8192 elems
#define BUF_D (2 * ASZ_D)            // 16384 elems = 32 KiB

__global__ __launch_bounds__(512, 2) void down_kernel(
    const __bf16* __restrict__ wsb, const float* __restrict__ b3,
    const float* __restrict__ probs, float* __restrict__ out,
    int e_base, size_t slotElems)
{
    __shared__ __align__(16) __bf16 lds[3 * BUF_D];
    const size_t MAT = (size_t)HID * FFN;
    const int tid = threadIdx.x;

    int f = blockIdx.y * GXD + blockIdx.x;
    f = (f & 7) * ((GXD * (TOK / BMD)) >> 3) + (f >> 3);
    const int bx = f >> 3;                 // 0..7
    const int by = f & 7;                  // 0..7

    const int e  = e_base + blockIdx.z;
    const int m0 = by * BMD;
    const int n0 = bx * BND;

    const __bf16* base = wsb + (size_t)blockIdx.z * slotElems;
    const __bf16* gA   = base + 3 * MAT + (size_t)m0 * FFN;   // h [T][F]
    const __bf16* gB   = base + 2 * MAT + (size_t)n0 * FFN;   // W3T [H][F]

    const int w = tid >> 6, lane = tid & 63;
    const int wm = w >> 2, wn = w & 3;          // 2M x 4N waves, per-wave 128x64
    const int fr = lane & 15, fq = lane >> 4;

    f32x4 acc[8][4] = {};

    const int NT = FFN / BKQ;  // 128

#pragma unroll
    for (int t0 = 0; t0 < 2; ++t0) {
        __bf16* d = lds + t0 * BUF_D;
        const size_t ko = (size_t)t0 * BKQ;
        stage256(d, gA + ko, FFN, tid);
        stage256(d + ASZ_D, gB + ko, FFN, tid);
    }
    asm volatile("s_waitcnt vmcnt(4)" ::: "memory");
    __builtin_amdgcn_s_barrier();

    int cur = 0;
    for (int t = 0; t < NT; ++t) {
        const int nb = (cur == 0) ? 2 : cur - 1;   // (cur+2)%3
        __bf16* d = lds + nb * BUF_D;
        const size_t ko2 = (size_t)(t + 2) * BKQ;
        const __bf16* bufA = lds + cur * BUF_D;
        const __bf16* bufB = bufA + ASZ_D;

        // ---- phase A: m-half 0 ----
        bf16x8 a0[4], b[4];
#pragma unroll
        for (int i = 0; i < 4; ++i) a0[i] = ldfrag32(bufA, wm * 128 + i * 16 + fr, fq);
#pragma unroll
        for (int j = 0; j < 4; ++j) b[j] = ldfrag32(bufB, wn * 64 + j * 16 + fr, fq);
        if (t + 2 < NT) stage256(d, gA + ko2, FFN, tid);           // 2 loads
        asm volatile("" ::: "memory");
        __builtin_amdgcn_s_barrier();
        __builtin_amdgcn_s_setprio(1);
#pragma unroll
        for (int j = 0; j < 4; ++j)
#pragma unroll
            for (int i = 0; i < 4; ++i)
                acc[i][j] = __builtin_amdgcn_mfma_f32_16x16x32_bf16(a0[i], b[j], acc[i][j], 0, 0, 0);
        __builtin_amdgcn_s_setprio(0);

        // ---- phase B: m-half 1 ----
        bf16x8 a1[4];
#pragma unroll
        for (int i = 0; i < 4; ++i) a1[i] = ldfrag32(bufA, wm * 128 + (i + 4) * 16 + fr, fq);
        if (t + 2 < NT) stage256(d + ASZ_D, gB + ko2, FFN, tid);   // 2 loads
        if (t + 1 < NT) {
            if (t + 2 < NT) asm volatile("s_waitcnt vmcnt(4)" ::: "memory");
            else            asm volatile("s_waitcnt vmcnt(0)" ::: "memory");
        }
        asm volatile("" ::: "memory");
        __builtin_amdgcn_s_barrier();
        __builtin_amdgcn_s_setprio(1);
#pragma unroll
        for (int j = 0; j < 4; ++j)
#pragma unroll
            for (int i = 0; i < 4; ++i)
                acc[i + 4][j] = __builtin_amdgcn_mfma_f32_16x16x32_bf16(a1[i], b[j], acc[i + 4][j], 0, 0, 0);
        __builtin_amdgcn_s_setprio(0);

        cur = (cur == 2) ? 0 : cur + 1;
    }

    float* gO = out + (size_t)(e * TOK + m0) * HID + n0;
    float bb3[4];
#pragma unroll
    for (int j = 0; j < 4; ++j) bb3[j] = b3[(size_t)e * HID + n0 + wn * 64 + j * 16 + fr];
#pragma unroll
    for (int i = 0; i < 8; ++i) {
#pragma unroll
        for (int r = 0; r < 4; ++r) {
            const int row = wm * 128 + i * 16 + fq * 4 + r;
            const float pp = probs[(size_t)e * TOK + m0 + row];
            float* o = gO + (size_t)row * HID;
#pragma unroll
            for (int j = 0; j < 4; ++j) {
                o[wn * 64 + j * 16 + fr] = (acc[i][j][r] + bb3[j]) * pp;
            }
        }
    }
}

extern "C" void kernel_launch(void* const* d_in, const int* in_sizes, int n_in,
                              void* d_out, int out_size, void* d_ws, size_t ws_size,
                              hipStream_t stream) {
    const float* X     = (const float*)d_in[0];
    // d_in[1] tokens_per_expert (int64): equal split, unused
    const float* probs = (const float*)d_in[2];
    const float* W1    = (const float*)d_in[3];
    const float* b1    = (const float*)d_in[4];
    const float* W2    = (const float*)d_in[5];
    const float* b2    = (const float*)d_in[6];
    const float* W3    = (const float*)d_in[7];
    const float* b3    = (const float*)d_in[8];
    float* out = (float*)d_out;

    const size_t MAT = (size_t)HID * FFN;                  // 8,388,608 elems
    const size_t XBE = (size_t)EXPERTS * TOK * HID;        // 33,554,432 elems
    const size_t slotElems = 4 * MAT;                      // W12(2), W3T, h

    int B = 4;  // measured best; B=8 regressed (r19), B=2 regressed (r7)
    while (B > 1 && ((size_t)B * slotElems + XBE) * sizeof(__bf16) > ws_size) B >>= 1;

    __bf16* wsb = (__bf16*)d_ws;
    __bf16* Xb  = wsb + (size_t)B * slotElems;

    // X -> bf16 once
    cvt_kernel<<<(int)(XBE / 8 / 256), 256, 0, stream>>>(X, Xb, XBE);

    for (int eb = 0; eb < EXPERTS; eb += B) {
        // merged: W1,W2 -> interleaved W12 [2F][H]; W3 -> W3T [H][F]
        transpose_all_kernel<<<dim3(2048, 3, B), 256, 0, stream>>>(
            W1, W2, W3, wsb, eb, slotElems);

        gateup_kernel<<<dim3(GXG, TOK / BMG, B), 512, 0, stream>>>(
            Xb, wsb, b1, b2, eb, slotElems);
        down_kernel<<<dim3(GXD, TOK / BMD, B), 512, 0, stream>>>(
            wsb, b3, probs, out, eb, slotElems);
    }
}